// Round 1
// baseline (643.820 us; speedup 1.0000x reference)
//
#include <hip/hip_runtime.h>
#include <stdint.h>

#define B_ 128
#define T_ 512
#define K_ 256
#define L2E 1.4426950408889634f
#define LN2 0.6931471805599453f

typedef _Float16 half2_t __attribute__((ext_vector_type(2)));

__device__ __forceinline__ float fdot2(uint32_t a, uint32_t b, float c) {
#if __has_builtin(__builtin_amdgcn_fdot2)
  return __builtin_amdgcn_fdot2(__builtin_bit_cast(half2_t, a),
                                __builtin_bit_cast(half2_t, b), c, false);
#else
  half2_t ha = __builtin_bit_cast(half2_t, a);
  half2_t hb = __builtin_bit_cast(half2_t, b);
  return c + (float)ha.x * (float)hb.x + (float)ha.y * (float)hb.y;
#endif
}

__device__ __forceinline__ float wave_max_f(float v) {
  #pragma unroll
  for (int off = 32; off; off >>= 1) v = fmaxf(v, __shfl_xor(v, off, 64));
  return v;
}
__device__ __forceinline__ float wave_sum_f(float v) {
  #pragma unroll
  for (int off = 32; off; off >>= 1) v += __shfl_xor(v, off, 64);
  return v;
}

// Epk[j][i2] = half2(exp(trans[2*i2][j]), exp(trans[2*i2+1][j]))
__global__ void prep_E(const float* __restrict__ trans, uint32_t* __restrict__ Ep) {
  int i2 = blockIdx.x;  // 0..127
  int j = threadIdx.x;  // 0..255
  float ea = expf(trans[(2 * i2) * K_ + j]);
  float eb = expf(trans[(2 * i2 + 1) * K_ + j]);
  half2_t p;
  p.x = (_Float16)ea;
  p.y = (_Float16)eb;
  Ep[j * 128 + i2] = __builtin_bit_cast(uint32_t, p);
}

__global__ __launch_bounds__(256, 1) void crf_fwd(
    const float* __restrict__ yp, const float* __restrict__ trans,
    const int* __restrict__ ytrue, const uint32_t* __restrict__ Ep,
    float* __restrict__ out) {
  const int b = blockIdx.x;
  const int tid = threadIdx.x;
  const int wv = tid >> 6;

  __shared__ uint32_t w_lds[128];  // 256 f16 weights, packed
  __shared__ float smax[4];
  __shared__ int sflag[4];
  __shared__ float sred[8];
  __shared__ int ys[T_];

  // E column for this thread -> registers (128 packed VGPRs)
  uint32_t E[128];
  {
    const uint4* src = (const uint4*)(Ep + tid * 128);
    #pragma unroll
    for (int k = 0; k < 32; ++k) {
      uint4 v = src[k];
      E[4 * k] = v.x; E[4 * k + 1] = v.y; E[4 * k + 2] = v.z; E[4 * k + 3] = v.w;
    }
  }

  ys[tid] = ytrue[b * T_ + tid];
  ys[tid + 256] = ytrue[b * T_ + 256 + tid];

  const float* ypb = yp + (size_t)b * T_ * K_;
  float x = ypb[tid];  // t = 0
  float xr1 = ypb[K_ + tid];      // prefetch t=1
  float xr2 = ypb[2 * K_ + tid];  // prefetch t=2

  unsigned long long bl = __ballot(x > -1000000.0f);
  if ((tid & 63) == 0) sflag[wv] = (bl == ~0ull) ? 1 : 0;
  __syncthreads();
  bool m0 = sflag[0] && sflag[1] && sflag[2] && sflag[3];
  float beta = m0 ? x * L2E : 0.0f;  // log2 domain
  float pacc = (m0 && tid == ys[0]) ? x : 0.0f;
  float tacc = 0.0f;
  bool mprev = m0;
  __syncthreads();  // protect sflag reuse (WAR across waves)

  #pragma unroll 1
  for (int t = 1; t < T_; ++t) {
    x = xr1; xr1 = xr2;
    if (t + 2 < T_) xr2 = ypb[(t + 2) * K_ + tid];
    float TR = 0.0f;
    if (tid == 0) TR = trans[ys[t - 1] * K_ + ys[t]];

    unsigned long long blt = __ballot(x > -1000000.0f);
    float wm = wave_max_f(beta);
    if ((tid & 63) == 0) { smax[wv] = wm; sflag[wv] = (blt == ~0ull) ? 1 : 0; }
    __syncthreads();  // bar1
    float M = fmaxf(fmaxf(smax[0], smax[1]), fmaxf(smax[2], smax[3]));
    bool m = sflag[0] && sflag[1] && sflag[2] && sflag[3];
    float w = exp2f(beta - M);  // in (0, 1]
    reinterpret_cast<_Float16*>(w_lds)[tid] = (_Float16)w;
    __syncthreads();  // bar2

    float a0 = 0.f, a1 = 0.f, a2 = 0.f, a3 = 0.f;
    const uint4* wq = (const uint4*)w_lds;
    #pragma unroll
    for (int k = 0; k < 32; ++k) {
      uint4 wvv = wq[k];  // broadcast b128 read: 8 weights
      a0 = fdot2(E[4 * k + 0], wvv.x, a0);
      a1 = fdot2(E[4 * k + 1], wvv.y, a1);
      a2 = fdot2(E[4 * k + 2], wvv.z, a2);
      a3 = fdot2(E[4 * k + 3], wvv.w, a3);
    }
    float S = (a0 + a1) + (a2 + a3);
    float nb = M + log2f(S) + x * L2E;

    if (m) {
      if (tid == ys[t]) pacc += x;
      if (mprev && tid == 0) tacc += TR;
      beta = nb;
    }
    mprev = m;
  }

  // final: log_norm = logsumexp(beta)/log2(e); subtract target score
  float wm = wave_max_f(beta);
  if ((tid & 63) == 0) smax[wv] = wm;
  __syncthreads();
  float Mf = fmaxf(fmaxf(smax[0], smax[1]), fmaxf(smax[2], smax[3]));
  float e = exp2f(beta - Mf);
  float s = wave_sum_f(e);
  float p = wave_sum_f(pacc);
  if ((tid & 63) == 0) { sred[wv] = s; sred[4 + wv] = p; }
  __syncthreads();
  if (tid == 0) {
    float S = (sred[0] + sred[1]) + (sred[2] + sred[3]);
    float P = (sred[4] + sred[5]) + (sred[6] + sred[7]);
    float logn = (Mf + log2f(S)) * LN2;
    out[b] = logn - (P + tacc);
  }
}

extern "C" void kernel_launch(void* const* d_in, const int* in_sizes, int n_in,
                              void* d_out, int out_size, void* d_ws, size_t ws_size,
                              hipStream_t stream) {
  const float* yp = (const float*)d_in[0];
  const float* trans = (const float*)d_in[1];
  const int* ytrue = (const int*)d_in[2];
  float* out = (float*)d_out;
  uint32_t* Ep = (uint32_t*)d_ws;  // 128 KB

  prep_E<<<dim3(128), dim3(256), 0, stream>>>(trans, Ep);
  crf_fwd<<<dim3(128), dim3(256), 0, stream>>>(yp, trans, ytrue, Ep, out);
}